// Round 4
// baseline (206.704 us; speedup 1.0000x reference)
//
#include <hip/hip_runtime.h>

// Observation kernel: B x 7 f32 rows -> B x 7 f32 rows, tiny uniform blocks(3,4).
// Memory-bound: ~235 MB round-trip, floor ~37us @ 6.3 TB/s achievable HBM
// (input may be L3-resident after the harness's d_in restore: 235 MB < 256 MiB).
// AoS row stride = 7 floats -> float4-coalesced global<->LDS staging with
// in-LDS transpose. Single 28 KiB LDS buffer reused in place.
// Barrier scheme (2 per tile):
//   load(slot k*TPB+t) -> B1 -> compute+writeback(own rows) -> B2 -> store(same slot)
// Store-read and next-tile load-write hit the SAME per-thread float4 slots, so
// per-thread program order covers the loop boundary; post-B2 slot accesses are
// thread-disjoint.
// Stride-7 scalar LDS access: 7 coprime 32 -> max 2 lanes/bank = free (m136).
// EXACT=true path (nrows % 1024 == 0, the benched shape): no bounds checks ->
// pure unrolled dwordx4 streams, max VMEM ops in flight per wave.

namespace {
constexpr float kL0  = 0.4f;
constexpr float kL1  = 0.08f;
constexpr float kYLo = 0.0f;
constexpr float kYHi = 2.0f;
constexpr float kFar = 10.0f;
constexpr int COLS = 7;
constexpr int TPB  = 256;
constexpr int ROWS = 1024;              // rows per tile
constexpr int RPT  = ROWS / TPB;        // 4 rows per thread
constexpr int TILE = ROWS * COLS;       // 7168 floats = 28 KiB = 1792 float4
}

template <bool EXACT>
__global__ __launch_bounds__(TPB) void obs_kernel(
    const float* __restrict__ state,
    const float* __restrict__ blocks,
    float* __restrict__ out,
    int nrows)
{
    __shared__ float lds[TILE];

    const int t = threadIdx.x;
    const long long ntot = (long long)nrows * COLS;
    const int ntiles = (nrows + ROWS - 1) / ROWS;

    // Blocks are tiny + wave-uniform: hoist to registers once.
    float bxl[3], bxr[3], byb[3], byt[3];
    #pragma unroll
    for (int i = 0; i < 3; ++i) {
        const float x  = blocks[i * 4 + 0];
        const float y  = blocks[i * 4 + 1];
        const float w2 = 0.5f * blocks[i * 4 + 2];
        const float h2 = 0.5f * blocks[i * 4 + 3];
        bxl[i] = x - w2;
        bxr[i] = x + w2;
        byb[i] = y - h2;
        byt[i] = y + h2;
    }

    for (int tile = blockIdx.x; tile < ntiles; tile += gridDim.x) {
        const long long f0 = (long long)tile * TILE;   // multiple of 4

        // ---- global -> LDS, float4 coalesced (16B/lane) ----
        #pragma unroll
        for (int k = 0; k < COLS; ++k) {
            const long long i4 = (f0 >> 2) + (long long)k * TPB + t;  // float4 idx
            float4 v;
            if (EXACT) {
                v = reinterpret_cast<const float4*>(state)[i4];
            } else {
                const long long fe = i4 * 4;
                v = make_float4(0.f, 0.f, 0.f, 0.f);
                if (fe + 3 < ntot) {
                    v = reinterpret_cast<const float4*>(state)[i4];
                } else if (fe < ntot) {
                    float tmp[4] = {0.f, 0.f, 0.f, 0.f};
                    #pragma unroll
                    for (int j = 0; j < 4; ++j) if (fe + j < ntot) tmp[j] = state[fe + j];
                    v = make_float4(tmp[0], tmp[1], tmp[2], tmp[3]);
                }
            }
            reinterpret_cast<float4*>(lds)[k * TPB + t] = v;
        }
        __syncthreads();   // B1: load-writes visible to compute-reads

        // ---- compute own rows, write results back in place ----
        #pragma unroll
        for (int rr = 0; rr < RPT; ++rr) {
            float* s = &lds[(t + rr * TPB) * COLS];
            // Capture ALL inputs before any overwrite.
            const float cx  = s[0];
            const float cy  = s[1];
            const float vx  = s[2];
            const float vy  = s[3];
            const float phi = s[4];

            float sa, ca;
            sincosf(fabsf(phi), &sa, &ca);   // cos(phi) == cos(|phi|)
            const float half_x = ca * (kL0 * 0.5f) + sa * (kL1 * 0.5f);
            const float half_y = sa * (kL0 * 0.5f) + ca * (kL1 * 0.5f);

            float up   = kYHi - cy - half_y;
            float down = cy - kYLo - half_y;
            float d1 = kFar, d2 = kFar;
            const float lo = cx - half_x;
            const float hi = cx + half_x;
            const float ylo_e = cy - half_y;   // capsule bottom edge
            const float yhi_e = cy + half_y;   // capsule top edge

            #pragma unroll
            for (int i = 0; i < 3; ++i) {
                const bool x_in = (bxl[i] <= hi && bxl[i] >= lo) ||
                                  (bxr[i] <= hi && bxr[i] >= lo);
                if (x_in) {
                    up   = byt[i] - cy - half_y;
                    down = cy - byb[i] - half_y;
                }
                const bool passed = hi < bxl[i];
                const float dist  = bxl[i] - cx - half_x;
                const bool y1_out = (ylo_e < byb[i]) || (ylo_e > byt[i]);
                const bool y2_out = (yhi_e > byt[i]) || (yhi_e < byb[i]);
                if (passed && y1_out && d1 == kFar) d1 = dist;  // first match wins
                if (passed && y2_out && d2 == kFar) d2 = dist;
            }

            // Out row: [d1, d2, up, down, v_x, v_y, phi]
            s[0] = d1;
            s[1] = d2;
            s[2] = up;
            s[3] = down;
            s[4] = vx;
            s[5] = vy;
            s[6] = phi;
        }
        __syncthreads();   // B2: writebacks visible to store-reads

        // ---- LDS -> global, float4 coalesced ----
        #pragma unroll
        for (int k = 0; k < COLS; ++k) {
            const long long i4 = (f0 >> 2) + (long long)k * TPB + t;
            const float4 v = reinterpret_cast<const float4*>(lds)[k * TPB + t];
            if (EXACT) {
                reinterpret_cast<float4*>(out)[i4] = v;
            } else {
                const long long fe = i4 * 4;
                if (fe + 3 < ntot) {
                    reinterpret_cast<float4*>(out)[i4] = v;
                } else if (fe < ntot) {
                    #pragma unroll
                    for (int j = 0; j < 4; ++j)
                        if (fe + j < ntot) out[fe + j] = (&v.x)[j];
                }
            }
        }
        // No barrier at loop boundary (see header comment).
    }
}

extern "C" void kernel_launch(void* const* d_in, const int* in_sizes, int n_in,
                              void* d_out, int out_size, void* d_ws, size_t ws_size,
                              hipStream_t stream) {
    const float* state  = (const float*)d_in[0];
    const float* blocks = (const float*)d_in[1];
    float* out = (float*)d_out;

    const int nrows = in_sizes[0] / COLS;
    const int ntiles = (nrows + ROWS - 1) / ROWS;
    const int grid = ntiles < 4096 ? ntiles : 4096;

    if (nrows % ROWS == 0) {
        obs_kernel<true ><<<grid, TPB, 0, stream>>>(state, blocks, out, nrows);
    } else {
        obs_kernel<false><<<grid, TPB, 0, stream>>>(state, blocks, out, nrows);
    }
}

// Round 6
// 205.995 us; speedup vs baseline: 1.0034x; 1.0034x over previous
//
#include <hip/hip_runtime.h>

// Observation kernel: B x 7 f32 rows -> B x 7 f32 rows, tiny uniform blocks(3,4).
// Round-4 rocprof (LDS-staged version): 77us @ 2.29 TB/s (29% peak), VALUBusy 12%,
// Occ 41% -> latency/barrier-structure-bound, NOT coalescing-bound (WRITE_SIZE
// exactly ideal, FETCH half-ideal via L3). Row stride = 28 B is sub-cache-line,
// so direct strided access touches the identical HBM lines as an LDS-transposed
// version. This version: no LDS, no barriers, 1 row/thread x4 unrolled (8
// independent VMEM loads in flight before compute), VGPR ~50 -> full occupancy.
// Only 5 of 7 input floats are live (cols 5,6 dead in output): load x4 + x1.

namespace {
constexpr float kL0  = 0.4f;
constexpr float kL1  = 0.08f;
constexpr float kYLo = 0.0f;
constexpr float kYHi = 2.0f;
constexpr float kFar = 10.0f;
constexpr int COLS = 7;
constexpr int TPB  = 256;
constexpr int UNR  = 4;
}

// 4-byte-aligned vector types: row base is only dword-aligned (7*r floats).
// gfx9 global ops require dword alignment only.
typedef float f4u __attribute__((ext_vector_type(4), aligned(4)));
typedef float f2u __attribute__((ext_vector_type(2), aligned(4)));

__global__ __launch_bounds__(TPB) void obs_kernel(
    const float* __restrict__ state,
    const float* __restrict__ blocks,
    float* __restrict__ out,
    int nrows)
{
    const int gtid = blockIdx.x * TPB + threadIdx.x;
    const int NT   = gridDim.x * TPB;

    // Tiny uniform blocks: hoist edges to registers once.
    float bxl[3], bxr[3], byb[3], byt[3];
    #pragma unroll
    for (int i = 0; i < 3; ++i) {
        const float x  = blocks[i * 4 + 0];
        const float y  = blocks[i * 4 + 1];
        const float w2 = 0.5f * blocks[i * 4 + 2];
        const float h2 = 0.5f * blocks[i * 4 + 3];
        bxl[i] = x - w2;
        bxr[i] = x + w2;
        byb[i] = y - h2;
        byt[i] = y + h2;
    }

    for (long long r0 = gtid; r0 < nrows; r0 += (long long)NT * UNR) {
        // ---- batch loads first: 8 independent VMEM ops in flight ----
        f4u   a[UNR];      // cx, cy, vx, vy
        float ph[UNR];     // phi (col 4); cols 5,6 are dead
        #pragma unroll
        for (int k = 0; k < UNR; ++k) {
            const long long r = r0 + (long long)k * NT;
            if (r < nrows) {
                const float* p = state + r * COLS;
                a[k]  = *reinterpret_cast<const f4u*>(p);
                ph[k] = p[4];
            }
        }

        // ---- compute + store per row ----
        #pragma unroll
        for (int k = 0; k < UNR; ++k) {
            const long long r = r0 + (long long)k * NT;
            if (r >= nrows) continue;

            const float cx  = a[k][0];
            const float cy  = a[k][1];
            const float vx  = a[k][2];
            const float vy  = a[k][3];
            const float phi = ph[k];

            float sa, ca;
            sincosf(fabsf(phi), &sa, &ca);   // cos(phi) == cos(|phi|)
            const float half_x = ca * (kL0 * 0.5f) + sa * (kL1 * 0.5f);
            const float half_y = sa * (kL0 * 0.5f) + ca * (kL1 * 0.5f);

            float up   = kYHi - cy - half_y;
            float down = cy - kYLo - half_y;
            float d1 = kFar, d2 = kFar;
            const float lo = cx - half_x;
            const float hi = cx + half_x;
            const float ylo_e = cy - half_y;   // capsule bottom edge
            const float yhi_e = cy + half_y;   // capsule top edge

            #pragma unroll
            for (int i = 0; i < 3; ++i) {
                const bool x_in = (bxl[i] <= hi && bxl[i] >= lo) ||
                                  (bxr[i] <= hi && bxr[i] >= lo);
                if (x_in) {
                    up   = byt[i] - cy - half_y;
                    down = cy - byb[i] - half_y;
                }
                const bool passed = hi < bxl[i];
                const float dist  = bxl[i] - cx - half_x;
                const bool y1_out = (ylo_e < byb[i]) || (ylo_e > byt[i]);
                const bool y2_out = (yhi_e > byt[i]) || (yhi_e < byb[i]);
                if (passed && y1_out && d1 == kFar) d1 = dist;  // first match wins
                if (passed && y2_out && d2 == kFar) d2 = dist;
            }

            // Out row: [d1, d2, up, down, v_x, v_y, phi]
            float* o = out + r * COLS;
            f4u o4 = {d1, d2, up, down};
            f2u o2 = {vx, vy};
            *reinterpret_cast<f4u*>(o)     = o4;
            *reinterpret_cast<f2u*>(o + 4) = o2;
            o[6] = phi;
        }
    }
}

extern "C" void kernel_launch(void* const* d_in, const int* in_sizes, int n_in,
                              void* d_out, int out_size, void* d_ws, size_t ws_size,
                              hipStream_t stream) {
    const float* state  = (const float*)d_in[0];
    const float* blocks = (const float*)d_in[1];
    float* out = (float*)d_out;

    const int nrows = in_sizes[0] / COLS;
    long long want = ((long long)nrows + TPB * UNR - 1) / (TPB * UNR);
    const int grid = (int)(want < 1 ? 1 : (want > 4096 ? 4096 : want));

    obs_kernel<<<grid, TPB, 0, stream>>>(state, blocks, out, nrows);
}